// Round 5
// baseline (213.403 us; speedup 1.0000x reference)
//
#include <hip/hip_runtime.h>
#include <hip/hip_bf16.h>
#include <math.h>

#define BB 4
#define II 2048
#define AA 2048
#define EE 256
#define HH 4

#define LOG2E 1.4426950408889634f
#define SCL   (0.125f * LOG2E)

typedef __bf16 bf16_t;
typedef bf16_t bf16x8 __attribute__((ext_vector_type(8)));
typedef bf16_t bf16x4 __attribute__((ext_vector_type(4)));
typedef float  f32x4  __attribute__((ext_vector_type(4)));

static __device__ __forceinline__ f32x4 mfma16(bf16x8 a, bf16x8 b, f32x4 c) {
    return __builtin_amdgcn_mfma_f32_16x16x32_bf16(a, b, c, 0, 0, 0);
}

// ---------------- fused pre-pass: Q/K/V projections + mass ----------------
// C[m][n] = sum_k A[m][k]*B[n][k], scaled by cscale.
// TRANS==1: Vt tiled store with PV-matched column permutation.
static __device__ __forceinline__ void proj_body(
    const float* __restrict__ Aop, const float* __restrict__ Bop,
    bf16_t* __restrict__ Cout, int m0, int n0, int TRANS, float cscale,
    bf16_t (*sA)[72], bf16_t (*sB)[72])
{
    const int t = threadIdx.x;
    const int w = t >> 6, l = t & 63, g = l >> 4, q = l & 15;
    const int wm = w >> 1, wn = w & 1;
    const int r = t >> 2, s = t & 3;

    f32x4 acc[2][2] = {};

    for (int kt = 0; kt < 4; ++kt) {
        {
            const float* ga = Aop + (size_t)(m0 + r) * EE + kt * 64 + s * 16;
            float tmp[16];
            *(f32x4*)&tmp[0]  = *(const f32x4*)(ga + 0);
            *(f32x4*)&tmp[4]  = *(const f32x4*)(ga + 4);
            *(f32x4*)&tmp[8]  = *(const f32x4*)(ga + 8);
            *(f32x4*)&tmp[12] = *(const f32x4*)(ga + 12);
            bf16x8 w0, w1;
            #pragma unroll
            for (int i = 0; i < 8; ++i) { w0[i] = (bf16_t)tmp[i]; w1[i] = (bf16_t)tmp[8 + i]; }
            *(bf16x8*)&sA[r][s * 16]     = w0;
            *(bf16x8*)&sA[r][s * 16 + 8] = w1;
        }
        {
            const float* gb = Bop + (size_t)(n0 + r) * EE + kt * 64 + s * 16;
            float tmp[16];
            *(f32x4*)&tmp[0]  = *(const f32x4*)(gb + 0);
            *(f32x4*)&tmp[4]  = *(const f32x4*)(gb + 4);
            *(f32x4*)&tmp[8]  = *(const f32x4*)(gb + 8);
            *(f32x4*)&tmp[12] = *(const f32x4*)(gb + 12);
            bf16x8 w0, w1;
            #pragma unroll
            for (int i = 0; i < 8; ++i) { w0[i] = (bf16_t)tmp[i]; w1[i] = (bf16_t)tmp[8 + i]; }
            *(bf16x8*)&sB[r][s * 16]     = w0;
            *(bf16x8*)&sB[r][s * 16 + 8] = w1;
        }
        __syncthreads();
        #pragma unroll
        for (int ks = 0; ks < 2; ++ks) {
            bf16x8 aA[2], aB[2];
            #pragma unroll
            for (int f = 0; f < 2; ++f) {
                aA[f] = *(const bf16x8*)&sA[wm * 32 + f * 16 + q][ks * 32 + g * 8];
                aB[f] = *(const bf16x8*)&sB[wn * 32 + f * 16 + q][ks * 32 + g * 8];
            }
            #pragma unroll
            for (int fm = 0; fm < 2; ++fm)
            #pragma unroll
            for (int fn = 0; fn < 2; ++fn)
                acc[fm][fn] = mfma16(aA[fm], aB[fn], acc[fm][fn]);
        }
        __syncthreads();
    }
    #pragma unroll
    for (int fm = 0; fm < 2; ++fm)
    #pragma unroll
    for (int fn = 0; fn < 2; ++fn)
    #pragma unroll
    for (int j = 0; j < 4; ++j) {
        const int m = m0 + wm * 32 + fm * 16 + g * 4 + j;
        const int n = n0 + wn * 32 + fn * 16 + q;
        const bf16_t v = (bf16_t)(acc[fm][fn][j] * cscale);
        if (TRANS == 0) {
            Cout[(size_t)m * EE + n] = v;
        } else {
            const int bb = n >> 11, a = n & (AA - 1);
            const int a6 = a & 63;
            const int p6 = (a6 & 32) | ((a6 & 12) << 1) | ((a6 & 16) >> 2) | (a6 & 3);
            Cout[(size_t)bb * (AA * EE) + (size_t)(a >> 6) * (EE * 64) + m * 64 + p6] = v;
        }
    }
}

__global__ __launch_bounds__(256) void fused_pre(
    const float* __restrict__ query, const float* __restrict__ key,
    const float* __restrict__ value, const float* __restrict__ in_w,
    const float* __restrict__ mass_w,
    bf16_t* __restrict__ Qp, bf16_t* __restrict__ Kp, bf16_t* __restrict__ Vt,
    float* __restrict__ massT)
{
    __shared__ __align__(16) bf16_t sA[64][72];
    __shared__ __align__(16) bf16_t sB[64][72];
    const int z = blockIdx.z;
    if (z == 0) {
        proj_body(query, in_w, Qp, blockIdx.x * 64, blockIdx.y * 64, 0, SCL, sA, sB);
    } else if (z == 1) {
        proj_body(key, in_w + 65536, Kp, blockIdx.x * 64, blockIdx.y * 64, 0, 1.0f, sA, sB);
    } else if (z == 2) {
        proj_body(in_w + 131072, value, Vt, blockIdx.y * 64, blockIdx.x * 64, 1, 1.0f, sA, sB);
    } else {
        // mass: massT[b][h][a] = log_cosh(key[b,a,:].mass_w[h,:]) * LOG2E
        const int w = threadIdx.x >> 6, l = threadIdx.x & 63;
        const int p = blockIdx.y * 128 + blockIdx.x;      // 0..511
        const int row0 = p * 16 + w * 4;
        f32x4 mw[HH];
        #pragma unroll
        for (int hh = 0; hh < HH; ++hh)
            mw[hh] = *(const f32x4*)(mass_w + hh * EE + l * 4);
        #pragma unroll
        for (int rr = 0; rr < 4; ++rr) {
            const int row = row0 + rr;                     // b*AA + a
            f32x4 kv = *(const f32x4*)(key + (size_t)row * EE + l * 4);
            f32x4 sd;
            #pragma unroll
            for (int hh = 0; hh < HH; ++hh)
                sd[hh] = kv[0]*mw[hh][0] + kv[1]*mw[hh][1] + kv[2]*mw[hh][2] + kv[3]*mw[hh][3];
            #pragma unroll
            for (int off = 32; off >= 1; off >>= 1) {
                #pragma unroll
                for (int hh = 0; hh < HH; ++hh) sd[hh] += __shfl_xor(sd[hh], off, 64);
            }
            if (l == 0) {
                const int bb = row >> 11, a = row & (AA - 1);
                #pragma unroll
                for (int hh = 0; hh < HH; ++hh) {
                    float ax = fabsf(sd[hh]);
                    massT[((size_t)bb * HH + hh) * AA + a] =
                        (ax + log1pf(__expf(-2.0f * ax)) - 0.693147180559945f) * LOG2E;
                }
            }
        }
    }
}

// out[m][n] = sum_k Obuf[m][k] * W[n][k]
__global__ __launch_bounds__(256) void out_gemm(
    const bf16_t* __restrict__ Aop, const float* __restrict__ Bop,
    float* __restrict__ Cout)
{
    __shared__ __align__(16) bf16_t sA[64][72];
    __shared__ __align__(16) bf16_t sB[64][72];
    const int t = threadIdx.x;
    const int w = t >> 6, l = t & 63, g = l >> 4, q = l & 15;
    const int wm = w >> 1, wn = w & 1;
    const int m0 = blockIdx.x * 64, n0 = blockIdx.y * 64;
    const int r = t >> 2, s = t & 3;

    f32x4 acc[2][2] = {};

    for (int kt = 0; kt < 4; ++kt) {
        {
            const bf16_t* ga = Aop + (size_t)(m0 + r) * EE + kt * 64 + s * 16;
            *(bf16x8*)&sA[r][s * 16]     = *(const bf16x8*)(ga);
            *(bf16x8*)&sA[r][s * 16 + 8] = *(const bf16x8*)(ga + 8);
        }
        {
            const float* gb = Bop + (size_t)(n0 + r) * EE + kt * 64 + s * 16;
            float tmp[16];
            *(f32x4*)&tmp[0]  = *(const f32x4*)(gb + 0);
            *(f32x4*)&tmp[4]  = *(const f32x4*)(gb + 4);
            *(f32x4*)&tmp[8]  = *(const f32x4*)(gb + 8);
            *(f32x4*)&tmp[12] = *(const f32x4*)(gb + 12);
            bf16x8 w0, w1;
            #pragma unroll
            for (int i = 0; i < 8; ++i) { w0[i] = (bf16_t)tmp[i]; w1[i] = (bf16_t)tmp[8 + i]; }
            *(bf16x8*)&sB[r][s * 16]     = w0;
            *(bf16x8*)&sB[r][s * 16 + 8] = w1;
        }
        __syncthreads();
        #pragma unroll
        for (int ks = 0; ks < 2; ++ks) {
            bf16x8 aA[2], aB[2];
            #pragma unroll
            for (int f = 0; f < 2; ++f) {
                aA[f] = *(const bf16x8*)&sA[wm * 32 + f * 16 + q][ks * 32 + g * 8];
                aB[f] = *(const bf16x8*)&sB[wn * 32 + f * 16 + q][ks * 32 + g * 8];
            }
            #pragma unroll
            for (int fm = 0; fm < 2; ++fm)
            #pragma unroll
            for (int fn = 0; fn < 2; ++fn)
                acc[fm][fn] = mfma16(aA[fm], aB[fn], acc[fm][fn]);
        }
        __syncthreads();
    }
    #pragma unroll
    for (int fm = 0; fm < 2; ++fm)
    #pragma unroll
    for (int fn = 0; fn < 2; ++fn)
    #pragma unroll
    for (int j = 0; j < 4; ++j) {
        const int m = m0 + wm * 32 + fm * 16 + g * 4 + j;
        const int n = n0 + wn * 32 + fn * 16 + q;
        Cout[(size_t)m * EE + n] = acc[fm][fn][j];
    }
}

// ---------------- fused flash attention, barrier-free ----------------
// 2048 blocks x 256 thr (4 waves). Block = 16 i-rows x one head; the 4 waves
// split the a-range 4-way (wave w: a-tiles w+4t). No in-loop LDS/barriers:
// K/V MFMA fragments are loaded directly global->reg (L2-resident; the p6
// column permutation of Vt makes each B-fragment one contiguous 16B chunk).
// dist (HBM) is prefetched one tile ahead. One final 4-way m/l/O combine.
// XCD-grouped block swizzle keeps each (b,h)'s K/V inside one XCD's L2.
__global__ __launch_bounds__(256, 4) void attn_kernel(
    const bf16_t* __restrict__ Qp, const bf16_t* __restrict__ Kp,
    const bf16_t* __restrict__ Vt, const float* __restrict__ massT,
    const float* __restrict__ dist, bf16_t* __restrict__ Obuf)
{
    __shared__ __align__(16) float cmb[3][64][25];   // +1 pad: stride 25 coprime 32

    const int t0 = threadIdx.x;
    const int w = t0 >> 6, l = t0 & 63, g = l >> 4, q = l & 15;

    // XCD-aware decode: consecutive blockIdx round-robin over 8 XCDs;
    // give each XCD 2 of the 16 (b,h) pairs -> 1MB K/V working set per L2.
    const int lin = blockIdx.x;
    const int xcd = lin & 7;
    const int r   = lin >> 3;
    const int bh  = xcd * 2 + (r >> 7);
    const int it  = r & 127;
    const int b = bh >> 2, h = bh & 3;
    const int i0 = it * 16;

    // Q fragments (pre-scaled by SCL at projection); rows i0+q (shared by all waves)
    bf16x8 qf[2];
    #pragma unroll
    for (int ks = 0; ks < 2; ++ks)
        qf[ks] = *(const bf16x8*)(Qp + (size_t)(b * II + i0 + q) * EE + h * 64 + ks * 32 + g * 8);

    // per-fa K row pointers (row = a0 + fa*16 + q), a0 starts at w*64
    const bf16_t* pK[4];
    #pragma unroll
    for (int fa = 0; fa < 4; ++fa)
        pK[fa] = Kp + ((size_t)b * AA + w * 64 + fa * 16 + q) * EE + h * 64 + g * 8;
    const bf16_t* pV = Vt + (size_t)b * (AA * EE) + (size_t)w * (EE * 64)
                          + (h * 64 + q) * 64 + g * 8;
    const float* pM = massT + ((size_t)b * HH + h) * AA + w * 64 + g * 4;
    const float* pD = dist + (size_t)(b * II + i0 + q) * AA + w * 64 + g * 4;

    // dist prefetch, named double-set (indices compile-time after unroll 2)
    f32x4 rd[2][4];
    #pragma unroll
    for (int fa = 0; fa < 4; ++fa) rd[0][fa] = *(const f32x4*)(pD + fa * 16);
    pD += 256;

    float mrun = -INFINITY;
    f32x4 oacc[4] = {};
    f32x4 lacc = {};
    bf16x8 vone;
    #pragma unroll
    for (int j = 0; j < 8; ++j) vone[j] = (bf16_t)1.0f;

    #pragma unroll 2
    for (int t = 0; t < 8; ++t) {
        // K fragments for this tile (L2)
        bf16x8 ak[4][2];
        #pragma unroll
        for (int fa = 0; fa < 4; ++fa)
        #pragma unroll
        for (int ks = 0; ks < 2; ++ks)
            ak[fa][ks] = *(const bf16x8*)(pK[fa] + ks * 32);

        // dist prefetch for next tile (HBM; full tile of cover)
        if (t < 7) {
            #pragma unroll
            for (int fa = 0; fa < 4; ++fa)
                rd[(t + 1) & 1][fa] = *(const f32x4*)(pD + fa * 16);
            pD += 256;
        }

        // ---- QK^T: S^T[a = fa*16+4g+j][i = q] ----
        f32x4 st[4] = {};
        __builtin_amdgcn_s_setprio(1);
        #pragma unroll
        for (int fa = 0; fa < 4; ++fa)
        #pragma unroll
        for (int ks = 0; ks < 2; ++ks)
            st[fa] = mfma16(ak[fa][ks], qf[ks], st[fa]);
        __builtin_amdgcn_s_setprio(0);

        // V fragments (issued here, consumed at PV; L2)
        bf16x8 vv[2][4];
        #pragma unroll
        for (int ka = 0; ka < 2; ++ka)
        #pragma unroll
        for (int fd = 0; fd < 4; ++fd)
            vv[ka][fd] = *(const bf16x8*)(pV + fd * (16 * 64) + ka * 32);

        // ---- bias (log2 domain) + row max ----
        float mloc = -INFINITY;
        #pragma unroll
        for (int fa = 0; fa < 4; ++fa) {
            f32x4 ms = *(const f32x4*)(pM + fa * 16);
            #pragma unroll
            for (int j = 0; j < 4; ++j) {
                float sv = fmaf(-ms[j], rd[t & 1][fa][j], st[fa][j]);
                st[fa][j] = sv;
                mloc = fmaxf(mloc, sv);
            }
        }

        // advance pointers
        #pragma unroll
        for (int fa = 0; fa < 4; ++fa) pK[fa] += 256 * EE;
        pV += 4 * (EE * 64);
        pM += 256;

        mloc = fmaxf(mloc, __shfl_xor(mloc, 16, 64));
        mloc = fmaxf(mloc, __shfl_xor(mloc, 32, 64));
        const bool skip = __all(mloc <= mrun + 8.0f);   // defer-max THR=8 (log2)
        float mnew = mrun;
        if (!skip) {
            mnew = fmaxf(mrun, mloc);
            const float sc = exp2f(mrun - mnew);
            mrun = mnew;
            float osc[4];
            #pragma unroll
            for (int j = 0; j < 4; ++j) osc[j] = __shfl(sc, g * 4 + j, 64);
            #pragma unroll
            for (int fd = 0; fd < 4; ++fd)
            #pragma unroll
            for (int j = 0; j < 4; ++j) oacc[fd][j] *= osc[j];
            #pragma unroll
            for (int j = 0; j < 4; ++j) lacc[j] *= osc[j];
        }

        // ---- P = exp2(S - m) ----
        #pragma unroll
        for (int fa = 0; fa < 4; ++fa)
        #pragma unroll
        for (int j = 0; j < 4; ++j)
            st[fa][j] = exp2f(st[fa][j] - mnew);

        // ---- pack P: slot (g,j) -> a = ka*32 + 16*(j>>2) + 4g + (j&3) ----
        bf16x8 pa[2];
        #pragma unroll
        for (int ka = 0; ka < 2; ++ka)
        #pragma unroll
        for (int j = 0; j < 8; ++j)
            pa[ka][j] = (bf16_t)st[2 * ka + (j >> 2)][j & 3];

        // ---- PV + ones-column denominator ----
        __builtin_amdgcn_s_setprio(1);
        #pragma unroll
        for (int ka = 0; ka < 2; ++ka) {
            #pragma unroll
            for (int fd = 0; fd < 4; ++fd)
                oacc[fd] = mfma16(pa[ka], vv[ka][fd], oacc[fd]);
            lacc = mfma16(pa[ka], vone, lacc);
        }
        __builtin_amdgcn_s_setprio(0);
    }

    // ---- 4-way cross-wave combine (the kernel's only barrier) ----
    if (w > 0) {
        float* p = &cmb[w - 1][l][0];
        p[0] = mrun;
        *(f32x4*)(p + 4) = lacc;
        #pragma unroll
        for (int fd = 0; fd < 4; ++fd) *(f32x4*)(p + 8 + fd * 4) = oacc[fd];
    }
    __syncthreads();
    if (w == 0) {
        float mS = mrun;
        float mW[3];
        #pragma unroll
        for (int u = 0; u < 3; ++u) { mW[u] = cmb[u][l][0]; mS = fmaxf(mS, mW[u]); }
        const float aS0 = exp2f(mrun - mS);
        float aSu[3];
        #pragma unroll
        for (int u = 0; u < 3; ++u) aSu[u] = exp2f(mW[u] - mS);
        float s0[4], su[3][4];
        #pragma unroll
        for (int j = 0; j < 4; ++j) {
            s0[j] = __shfl(aS0, g * 4 + j, 64);
            #pragma unroll
            for (int u = 0; u < 3; ++u) su[u][j] = __shfl(aSu[u], g * 4 + j, 64);
        }
        float inv[4];
        #pragma unroll
        for (int j = 0; j < 4; ++j) {
            float ls = lacc[j] * s0[j];
            #pragma unroll
            for (int u = 0; u < 3; ++u) ls += cmb[u][l][4 + j] * su[u][j];
            inv[j] = 1.0f / ls;
        }
        #pragma unroll
        for (int fd = 0; fd < 4; ++fd)
        #pragma unroll
        for (int j = 0; j < 4; ++j) {
            float o = oacc[fd][j] * s0[j];
            #pragma unroll
            for (int u = 0; u < 3; ++u) o += cmb[u][l][8 + fd * 4 + j] * su[u][j];
            Obuf[(size_t)(b * II + i0 + g * 4 + j) * EE + h * 64 + fd * 16 + q] =
                (bf16_t)(o * inv[j]);
        }
    }
}

extern "C" void kernel_launch(void* const* d_in, const int* in_sizes, int n_in,
                              void* d_out, int out_size, void* d_ws, size_t ws_size,
                              hipStream_t stream)
{
    const float* query  = (const float*)d_in[0];
    const float* key    = (const float*)d_in[1];
    const float* value  = (const float*)d_in[2];
    const float* dist   = (const float*)d_in[3];
    const float* in_w   = (const float*)d_in[4];
    const float* out_w  = (const float*)d_in[5];
    const float* mass_w = (const float*)d_in[6];
    float* out = (float*)d_out;

    char* ws = (char*)d_ws;
    bf16_t* Qp    = (bf16_t*)(ws);
    bf16_t* Kp    = (bf16_t*)(ws + 1 * 4194304);
    bf16_t* Vt    = (bf16_t*)(ws + 2 * 4194304);
    bf16_t* Obuf  = (bf16_t*)(ws + 3 * 4194304);
    float*  massT = (float*) (ws + 4 * 4194304);

    fused_pre<<<dim3(128, 4, 4), dim3(256), 0, stream>>>(
        query, key, value, in_w, mass_w, Qp, Kp, Vt, massT);
    attn_kernel<<<dim3(2048), dim3(256), 0, stream>>>(Qp, Kp, Vt, massT, dist, Obuf);
    out_gemm<<<dim3(128, 4), dim3(256), 0, stream>>>(Obuf, out_w, out);
}

// Round 6
// 85.536 us; speedup vs baseline: 2.4949x; 2.4949x over previous
//
#include <hip/hip_runtime.h>
#include <hip/hip_bf16.h>
#include <math.h>

#define BB 4
#define II 2048
#define AA 2048
#define EE 256
#define HH 4

#define LOG2E 1.4426950408889634f
#define SCL   (0.125f * LOG2E)

typedef __bf16 bf16_t;
typedef bf16_t bf16x8 __attribute__((ext_vector_type(8)));
typedef bf16_t bf16x4 __attribute__((ext_vector_type(4)));
typedef float  f32x4  __attribute__((ext_vector_type(4)));

static __device__ __forceinline__ f32x4 mfma16(bf16x8 a, bf16x8 b, f32x4 c) {
    return __builtin_amdgcn_mfma_f32_16x16x32_bf16(a, b, c, 0, 0, 0);
}

static __device__ __forceinline__ void glds16(const bf16_t* g, const bf16_t* l) {
    __builtin_amdgcn_global_load_lds(
        (const __attribute__((address_space(1))) void*)g,
        (__attribute__((address_space(3))) void*)l, 16, 0, 0);
}

// ---------------- fused pre-pass: Q/K/V projections + mass ----------------
// C[m][n] = sum_k A[m][k]*B[n][k], scaled by cscale.
// TRANS==1: Vt tiled store with PV-matched column permutation.
static __device__ __forceinline__ void proj_body(
    const float* __restrict__ Aop, const float* __restrict__ Bop,
    bf16_t* __restrict__ Cout, int m0, int n0, int TRANS, float cscale,
    bf16_t (*sA)[72], bf16_t (*sB)[72])
{
    const int t = threadIdx.x;
    const int w = t >> 6, l = t & 63, g = l >> 4, q = l & 15;
    const int wm = w >> 1, wn = w & 1;
    const int r = t >> 2, s = t & 3;

    f32x4 acc[2][2] = {};

    for (int kt = 0; kt < 4; ++kt) {
        {
            const float* ga = Aop + (size_t)(m0 + r) * EE + kt * 64 + s * 16;
            float tmp[16];
            *(f32x4*)&tmp[0]  = *(const f32x4*)(ga + 0);
            *(f32x4*)&tmp[4]  = *(const f32x4*)(ga + 4);
            *(f32x4*)&tmp[8]  = *(const f32x4*)(ga + 8);
            *(f32x4*)&tmp[12] = *(const f32x4*)(ga + 12);
            bf16x8 w0, w1;
            #pragma unroll
            for (int i = 0; i < 8; ++i) { w0[i] = (bf16_t)tmp[i]; w1[i] = (bf16_t)tmp[8 + i]; }
            *(bf16x8*)&sA[r][s * 16]     = w0;
            *(bf16x8*)&sA[r][s * 16 + 8] = w1;
        }
        {
            const float* gb = Bop + (size_t)(n0 + r) * EE + kt * 64 + s * 16;
            float tmp[16];
            *(f32x4*)&tmp[0]  = *(const f32x4*)(gb + 0);
            *(f32x4*)&tmp[4]  = *(const f32x4*)(gb + 4);
            *(f32x4*)&tmp[8]  = *(const f32x4*)(gb + 8);
            *(f32x4*)&tmp[12] = *(const f32x4*)(gb + 12);
            bf16x8 w0, w1;
            #pragma unroll
            for (int i = 0; i < 8; ++i) { w0[i] = (bf16_t)tmp[i]; w1[i] = (bf16_t)tmp[8 + i]; }
            *(bf16x8*)&sB[r][s * 16]     = w0;
            *(bf16x8*)&sB[r][s * 16 + 8] = w1;
        }
        __syncthreads();
        #pragma unroll
        for (int ks = 0; ks < 2; ++ks) {
            bf16x8 aA[2], aB[2];
            #pragma unroll
            for (int f = 0; f < 2; ++f) {
                aA[f] = *(const bf16x8*)&sA[wm * 32 + f * 16 + q][ks * 32 + g * 8];
                aB[f] = *(const bf16x8*)&sB[wn * 32 + f * 16 + q][ks * 32 + g * 8];
            }
            #pragma unroll
            for (int fm = 0; fm < 2; ++fm)
            #pragma unroll
            for (int fn = 0; fn < 2; ++fn)
                acc[fm][fn] = mfma16(aA[fm], aB[fn], acc[fm][fn]);
        }
        __syncthreads();
    }
    #pragma unroll
    for (int fm = 0; fm < 2; ++fm)
    #pragma unroll
    for (int fn = 0; fn < 2; ++fn)
    #pragma unroll
    for (int j = 0; j < 4; ++j) {
        const int m = m0 + wm * 32 + fm * 16 + g * 4 + j;
        const int n = n0 + wn * 32 + fn * 16 + q;
        const bf16_t v = (bf16_t)(acc[fm][fn][j] * cscale);
        if (TRANS == 0) {
            Cout[(size_t)m * EE + n] = v;
        } else {
            const int bb = n >> 11, a = n & (AA - 1);
            const int a6 = a & 63;
            const int p6 = (a6 & 32) | ((a6 & 12) << 1) | ((a6 & 16) >> 2) | (a6 & 3);
            Cout[(size_t)bb * (AA * EE) + (size_t)(a >> 6) * (EE * 64) + m * 64 + p6] = v;
        }
    }
}

__global__ __launch_bounds__(256) void fused_pre(
    const float* __restrict__ query, const float* __restrict__ key,
    const float* __restrict__ value, const float* __restrict__ in_w,
    const float* __restrict__ mass_w,
    bf16_t* __restrict__ Qp, bf16_t* __restrict__ Kp, bf16_t* __restrict__ Vt,
    float* __restrict__ massT)
{
    __shared__ __align__(16) bf16_t sA[64][72];
    __shared__ __align__(16) bf16_t sB[64][72];
    const int z = blockIdx.z;
    if (z == 0) {
        proj_body(query, in_w, Qp, blockIdx.x * 64, blockIdx.y * 64, 0, SCL, sA, sB);
    } else if (z == 1) {
        proj_body(key, in_w + 65536, Kp, blockIdx.x * 64, blockIdx.y * 64, 0, 1.0f, sA, sB);
    } else if (z == 2) {
        proj_body(in_w + 131072, value, Vt, blockIdx.y * 64, blockIdx.x * 64, 1, 1.0f, sA, sB);
    } else {
        // mass: massT[b][h][a] = log_cosh(key[b,a,:].mass_w[h,:]) * LOG2E
        const int w = threadIdx.x >> 6, l = threadIdx.x & 63;
        const int p = blockIdx.y * 128 + blockIdx.x;      // 0..511
        const int row0 = p * 16 + w * 4;
        f32x4 mw[HH];
        #pragma unroll
        for (int hh = 0; hh < HH; ++hh)
            mw[hh] = *(const f32x4*)(mass_w + hh * EE + l * 4);
        #pragma unroll
        for (int rr = 0; rr < 4; ++rr) {
            const int row = row0 + rr;                     // b*AA + a
            f32x4 kv = *(const f32x4*)(key + (size_t)row * EE + l * 4);
            f32x4 sd;
            #pragma unroll
            for (int hh = 0; hh < HH; ++hh)
                sd[hh] = kv[0]*mw[hh][0] + kv[1]*mw[hh][1] + kv[2]*mw[hh][2] + kv[3]*mw[hh][3];
            #pragma unroll
            for (int off = 32; off >= 1; off >>= 1) {
                #pragma unroll
                for (int hh = 0; hh < HH; ++hh) sd[hh] += __shfl_xor(sd[hh], off, 64);
            }
            if (l == 0) {
                const int bb = row >> 11, a = row & (AA - 1);
                #pragma unroll
                for (int hh = 0; hh < HH; ++hh) {
                    float ax = fabsf(sd[hh]);
                    massT[((size_t)bb * HH + hh) * AA + a] =
                        (ax + log1pf(__expf(-2.0f * ax)) - 0.693147180559945f) * LOG2E;
                }
            }
        }
    }
}

// out[m][n] = sum_k Obuf[m][k] * W[n][k]
__global__ __launch_bounds__(256) void out_gemm(
    const bf16_t* __restrict__ Aop, const float* __restrict__ Bop,
    float* __restrict__ Cout)
{
    __shared__ __align__(16) bf16_t sA[64][72];
    __shared__ __align__(16) bf16_t sB[64][72];
    const int t = threadIdx.x;
    const int w = t >> 6, l = t & 63, g = l >> 4, q = l & 15;
    const int wm = w >> 1, wn = w & 1;
    const int m0 = blockIdx.x * 64, n0 = blockIdx.y * 64;
    const int r = t >> 2, s = t & 3;

    f32x4 acc[2][2] = {};

    for (int kt = 0; kt < 4; ++kt) {
        {
            const bf16_t* ga = Aop + (size_t)(m0 + r) * EE + kt * 64 + s * 16;
            *(bf16x8*)&sA[r][s * 16]     = *(const bf16x8*)(ga);
            *(bf16x8*)&sA[r][s * 16 + 8] = *(const bf16x8*)(ga + 8);
        }
        {
            const float* gb = Bop + (size_t)(n0 + r) * EE + kt * 64 + s * 16;
            float tmp[16];
            *(f32x4*)&tmp[0]  = *(const f32x4*)(gb + 0);
            *(f32x4*)&tmp[4]  = *(const f32x4*)(gb + 4);
            *(f32x4*)&tmp[8]  = *(const f32x4*)(gb + 8);
            *(f32x4*)&tmp[12] = *(const f32x4*)(gb + 12);
            bf16x8 w0, w1;
            #pragma unroll
            for (int i = 0; i < 8; ++i) { w0[i] = (bf16_t)tmp[i]; w1[i] = (bf16_t)tmp[8 + i]; }
            *(bf16x8*)&sB[r][s * 16]     = w0;
            *(bf16x8*)&sB[r][s * 16 + 8] = w1;
        }
        __syncthreads();
        #pragma unroll
        for (int ks = 0; ks < 2; ++ks) {
            bf16x8 aA[2], aB[2];
            #pragma unroll
            for (int f = 0; f < 2; ++f) {
                aA[f] = *(const bf16x8*)&sA[wm * 32 + f * 16 + q][ks * 32 + g * 8];
                aB[f] = *(const bf16x8*)&sB[wn * 32 + f * 16 + q][ks * 32 + g * 8];
            }
            #pragma unroll
            for (int fm = 0; fm < 2; ++fm)
            #pragma unroll
            for (int fn = 0; fn < 2; ++fn)
                acc[fm][fn] = mfma16(aA[fm], aB[fn], acc[fm][fn]);
        }
        __syncthreads();
    }
    #pragma unroll
    for (int fm = 0; fm < 2; ++fm)
    #pragma unroll
    for (int fn = 0; fn < 2; ++fn)
    #pragma unroll
    for (int j = 0; j < 4; ++j) {
        const int m = m0 + wm * 32 + fm * 16 + g * 4 + j;
        const int n = n0 + wn * 32 + fn * 16 + q;
        Cout[(size_t)m * EE + n] = acc[fm][fn][j];
    }
}

// ---------------- fused flash attention ----------------
// Grid (32,4,4) x 512 threads = 8 waves: parity s = wv>>2 (a-tiles 2k+s),
// row-group rg = wv&3 (16 i-rows). Per-parity double-buffered K/V LDS via
// global_load_lds (pre-swizzled source, linear dest). Denominator via
// ones-column MFMA. Defer-max THR=8. Counted-vmcnt barrier (T4): dist loads
// stay in flight across the per-tile barrier; only glds drain.
__global__ __launch_bounds__(512, 4) void attn_kernel(
    const bf16_t* __restrict__ Qp, const bf16_t* __restrict__ Kp,
    const bf16_t* __restrict__ Vt, const float* __restrict__ massT,
    const float* __restrict__ dist, bf16_t* __restrict__ Obuf)
{
    __shared__ __align__(16) bf16_t sK[2][2][4096];   // [parity][buf][64a x 64d] chunk^=(row&7)
    __shared__ __align__(16) bf16_t sV[2][2][4096];   // [parity][buf][64d x 64a'] chunk^=(row&7)
    __shared__ __align__(16) float  sM[2048];         // mass row (log2 domain)

    const int t = threadIdx.x;
    const int wv = t >> 6, l = t & 63, g = l >> 4, q = l & 15;
    const int s = wv >> 2, rg = wv & 3;
    const int h = blockIdx.y, b = blockIdx.z;
    const int i0 = blockIdx.x * 64;

    *(f32x4*)&sM[t * 4] = *(const f32x4*)(massT + ((size_t)b * HH + h) * AA + t * 4);

    // Q fragments (pre-scaled by SCL at projection)
    bf16x8 qf[2];
    #pragma unroll
    for (int ks = 0; ks < 2; ++ks)
        qf[ks] = *(const bf16x8*)(Qp + (size_t)(b * II + i0 + rg * 16 + q) * EE
                                     + h * 64 + ks * 32 + g * 8);

    // staging geometry: wave rg writes rows [rg*16, rg*16+16), lane covers (row, chunk)
    const int u0 = rg * 2;
    const int drow0 = u0 * 8 + (l >> 3);
    const int cs = (l & 7) ^ (drow0 & 7);   // constant pre-swizzled source chunk

    // incremental global pointers (parity stream starts at a0 = s*64)
    const bf16_t* pkg = Kp + ((size_t)b * AA + s * 64 + drow0) * EE + h * 64 + cs * 8;
    const bf16_t* pvg = Vt + (size_t)b * (AA * EE) + (size_t)s * (EE * 64)
                           + (size_t)(h * 64 + drow0) * 64 + cs * 8;
    const float*  pdg = dist + ((size_t)b * II + i0 + rg * 16 + q) * AA + s * 64 + g * 4;

    auto stage = [&](int kb) {
        #pragma unroll
        for (int u = 0; u < 2; ++u) {
            glds16(pkg + u * (8 * EE), &sK[s][kb][(u0 + u) * 512]);
            glds16(pvg + u * (8 * 64), &sV[s][kb][(u0 + u) * 512]);
        }
    };

    // dist double-set (indices compile-time after unroll 2)
    f32x4 rd[2][4];

    stage(0);
    pkg += 128 * EE; pvg += 2 * (EE * 64);
    #pragma unroll
    for (int fa = 0; fa < 4; ++fa) rd[0][fa] = *(const f32x4*)(pdg + fa * 16);
    pdg += 128;
    __syncthreads();

    float mrun = -INFINITY;
    f32x4 oacc[4] = {};
    f32x4 lacc = {};
    bf16x8 vone;
    #pragma unroll
    for (int j = 0; j < 8; ++j) vone[j] = (bf16_t)1.0f;

    int ma = s * 64;    // sM element offset for this tile

    #pragma unroll 2
    for (int k = 0; k < 16; ++k) {
        const int kb = k & 1;
        if (k < 15) {
            stage(kb ^ 1);                         // 4 glds (drained at this iter's barrier)
            pkg += 128 * EE; pvg += 2 * (EE * 64);
            #pragma unroll
            for (int fa = 0; fa < 4; ++fa)         // 4 dist loads (fly across the barrier)
                rd[(k + 1) & 1][fa] = *(const f32x4*)(pdg + fa * 16);
            pdg += 128;
        }

        // ---- QK^T: S^T[a = fa*16+4g+j][i = q] ----
        f32x4 st[4] = {};
        __builtin_amdgcn_s_setprio(1);
        #pragma unroll
        for (int fa = 0; fa < 4; ++fa) {
            const int row = fa * 16 + q;
            #pragma unroll
            for (int ks = 0; ks < 2; ++ks) {
                bf16x8 ak = *(const bf16x8*)&sK[s][kb][row * 64 + (((ks * 4 + g) ^ (row & 7)) * 8)];
                st[fa] = mfma16(ak, qf[ks], st[fa]);
            }
        }
        __builtin_amdgcn_s_setprio(0);

        // ---- bias (log2 domain, scale pre-folded) + row max ----
        float mloc = -INFINITY;
        #pragma unroll
        for (int fa = 0; fa < 4; ++fa) {
            f32x4 ms = *(const f32x4*)&sM[ma + fa * 16 + g * 4];
            #pragma unroll
            for (int j = 0; j < 4; ++j) {
                float sv = fmaf(-ms[j], rd[k & 1][fa][j], st[fa][j]);
                st[fa][j] = sv;
                mloc = fmaxf(mloc, sv);
            }
        }
        ma += 128;

        mloc = fmaxf(mloc, __shfl_xor(mloc, 16, 64));
        mloc = fmaxf(mloc, __shfl_xor(mloc, 32, 64));
        const bool skip = __all(mloc <= mrun + 8.0f);   // defer-max THR=8 (log2)
        float mnew = mrun;
        if (!skip) {
            mnew = fmaxf(mrun, mloc);
            const float sc = exp2f(mrun - mnew);
            mrun = mnew;
            float osc[4];
            #pragma unroll
            for (int j = 0; j < 4; ++j) osc[j] = __shfl(sc, g * 4 + j, 64);
            #pragma unroll
            for (int fd = 0; fd < 4; ++fd)
            #pragma unroll
            for (int j = 0; j < 4; ++j) oacc[fd][j] *= osc[j];
            #pragma unroll
            for (int j = 0; j < 4; ++j) lacc[j] *= osc[j];
        }

        // ---- P = exp2(S - m) ----
        #pragma unroll
        for (int fa = 0; fa < 4; ++fa)
        #pragma unroll
        for (int j = 0; j < 4; ++j)
            st[fa][j] = exp2f(st[fa][j] - mnew);

        // ---- pack P: slot (g,j) -> a = ka*32 + 16*(j>>2) + 4g + (j&3) ----
        bf16x8 pa[2];
        #pragma unroll
        for (int ka = 0; ka < 2; ++ka)
        #pragma unroll
        for (int j = 0; j < 8; ++j)
            pa[ka][j] = (bf16_t)st[2 * ka + (j >> 2)][j & 3];

        // ---- PV + ones-column denominator ----
        __builtin_amdgcn_s_setprio(1);
        #pragma unroll
        for (int ka = 0; ka < 2; ++ka) {
            #pragma unroll
            for (int fd = 0; fd < 4; ++fd) {
                const int row = fd * 16 + q;
                bf16x8 bv = *(const bf16x8*)&sV[s][kb][row * 64 + (((ka * 4 + g) ^ (row & 7)) * 8)];
                oacc[fd] = mfma16(pa[ka], bv, oacc[fd]);
            }
            lacc = mfma16(pa[ka], vone, lacc);
        }
        __builtin_amdgcn_s_setprio(0);

        if (k < 15) {
            // T4 counted barrier: drain the 4 glds (newest-4 = dist stay in flight).
            // 0x0F74 = vmcnt(4), expcnt/lgkmcnt no-wait.
            __builtin_amdgcn_s_waitcnt(0x0F74);
            __builtin_amdgcn_s_barrier();
        }
    }
    __syncthreads();   // full drain before cmb aliases sK

    // ---- parity combine (reuse sK region) + store ----
    // slot: 24 floats: [0]=mrun, [4..7]=lacc, [8..23]=oacc
    float* cb = (float*)&sK[0][0][0];
    if (s == 1) {
        float* p = cb + (rg * 64 + l) * 24;
        p[0] = mrun;
        *(f32x4*)(p + 4) = lacc;
        #pragma unroll
        for (int fd = 0; fd < 4; ++fd) *(f32x4*)(p + 8 + fd * 4) = oacc[fd];
    }
    __syncthreads();
    if (s == 0) {
        const float* p = cb + (rg * 64 + l) * 24;
        const float mB = p[0];
        const f32x4 lB = *(const f32x4*)(p + 4);
        const float mS = fmaxf(mrun, mB);
        const float aS = exp2f(mrun - mS), bS = exp2f(mB - mS);
        float aSo[4], bSo[4], inv[4];
        #pragma unroll
        for (int j = 0; j < 4; ++j) {
            aSo[j] = __shfl(aS, g * 4 + j, 64);
            bSo[j] = __shfl(bS, g * 4 + j, 64);
        }
        #pragma unroll
        for (int j = 0; j < 4; ++j)
            inv[j] = 1.0f / (lacc[j] * aSo[j] + lB[j] * bSo[j]);
        #pragma unroll
        for (int fd = 0; fd < 4; ++fd) {
            f32x4 ob = *(const f32x4*)(p + 8 + fd * 4);
            #pragma unroll
            for (int j = 0; j < 4; ++j) {
                const float o = (oacc[fd][j] * aSo[j] + ob[j] * bSo[j]) * inv[j];
                Obuf[(size_t)(b * II + i0 + rg * 16 + g * 4 + j) * EE
                     + h * 64 + fd * 16 + q] = (bf16_t)o;
            }
        }
    }
}

extern "C" void kernel_launch(void* const* d_in, const int* in_sizes, int n_in,
                              void* d_out, int out_size, void* d_ws, size_t ws_size,
                              hipStream_t stream)
{
    const float* query  = (const float*)d_in[0];
    const float* key    = (const float*)d_in[1];
    const float* value  = (const float*)d_in[2];
    const float* dist   = (const float*)d_in[3];
    const float* in_w   = (const float*)d_in[4];
    const float* out_w  = (const float*)d_in[5];
    const float* mass_w = (const float*)d_in[6];
    float* out = (float*)d_out;

    char* ws = (char*)d_ws;
    bf16_t* Qp    = (bf16_t*)(ws);
    bf16_t* Kp    = (bf16_t*)(ws + 1 * 4194304);
    bf16_t* Vt    = (bf16_t*)(ws + 2 * 4194304);
    bf16_t* Obuf  = (bf16_t*)(ws + 3 * 4194304);
    float*  massT = (float*) (ws + 4 * 4194304);

    fused_pre<<<dim3(128, 4, 4), dim3(256), 0, stream>>>(
        query, key, value, in_w, mass_w, Qp, Kp, Vt, massT);
    attn_kernel<<<dim3(32, 4, 4), dim3(512), 0, stream>>>(Qp, Kp, Vt, massT, dist, Obuf);
    out_gemm<<<dim3(128, 4), dim3(256), 0, stream>>>(Obuf, out_w, out);
}